// Round 12
// baseline (388.905 us; speedup 1.0000x reference)
//
#include <hip/hip_runtime.h>
#include <math.h>

#define N_TOK 8192
#define D_FEAT 768
#define K_EIG 256
#define KNN 10
#define CAP 256
#define NCHUNK 4
#define CHUNK 2048

typedef unsigned short ushort_t;
typedef float f32x4 __attribute__((ext_vector_type(4)));
typedef short bf16x8 __attribute__((ext_vector_type(8)));
typedef unsigned short u16x8 __attribute__((ext_vector_type(8)));
typedef unsigned short u16x4 __attribute__((ext_vector_type(4)));

__device__ inline float u2f(unsigned u) { union { unsigned u; float f; } c; c.u = u; return c.f; }
__device__ inline unsigned f2u(float f) { union { unsigned u; float f; } c; c.f = f; return c.u; }
__device__ inline ushort_t f2bf_rne(float f) {
  const unsigned u = f2u(f);
  return (ushort_t)((u + 0x7fffu + ((u >> 16) & 1u)) >> 16);
}
// monotone u16 key from f32 (truncate to bf16, flip for total order)
__device__ inline ushort_t f2key(float f) {
  const unsigned h = f2u(f) >> 16;
  return (ushort_t)((h & 0x8000u) ? (h ^ 0xFFFFu) : (h | 0x8000u));
}
__device__ inline float key2f(unsigned k) {
  const unsigned h = (k & 0x8000u) ? (k ^ 0x8000u) : (k ^ 0xFFFFu);
  return u2f(h << 16);
}
__device__ inline unsigned wave_max_u32(unsigned m) {
#pragma unroll
  for (int s = 1; s < 64; s <<= 1) m = max(m, (unsigned)__shfl_xor((int)m, s, 64));
  return m;
}

// ---------- kernel 1: row stats + bf16 normalized copy (vectorized) ----------
__global__ __launch_bounds__(192) void k_norm(const float* __restrict__ FF,
                                              ushort_t* __restrict__ FFbf,
                                              float* __restrict__ rn,
                                              float* __restrict__ sqv) {
  const int row = blockIdx.x;
  const int tid = threadIdx.x;
  const float4 v = *(const float4*)&FF[(size_t)row * D_FEAT + tid * 4];
  float s = v.x * v.x + v.y * v.y + v.z * v.z + v.w * v.w;
  __shared__ float red[3];
  for (int m = 32; m > 0; m >>= 1) s += __shfl_xor(s, m, 64);
  if ((tid & 63) == 0) red[tid >> 6] = s;
  __syncthreads();
  const float tot = red[0] + red[1] + red[2];
  const float scale = 1.f / fmaxf(sqrtf(tot), 1e-12f);
  float4 w;
  w.x = v.x * scale; w.y = v.y * scale; w.z = v.z * scale; w.w = v.w * scale;
  float s2 = w.x * w.x + w.y * w.y + w.z * w.z + w.w * w.w;
  u16x4 o;
  o[0] = f2bf_rne(w.x); o[1] = f2bf_rne(w.y); o[2] = f2bf_rne(w.z); o[3] = f2bf_rne(w.w);
  *(u16x4*)&FFbf[(size_t)row * D_FEAT + tid * 4] = o;
  for (int m = 32; m > 0; m >>= 1) s2 += __shfl_xor(s2, m, 64);
  __syncthreads();
  if ((tid & 63) == 0) red[tid >> 6] = s2;
  __syncthreads();
  if (tid == 0) { sqv[row] = red[0] + red[1] + red[2]; rn[row] = scale; }
}

// ---------- kernel 2: 256x256-tile bf16 MFMA GEMM, 4 waves x (128x128)/wave ----------
// 256 threads = 4 waves (2M x 2N), per-wave 128x128 (8x8 fragments), BK=32.
// Rationale: 16 ds_read_b128 per 64 MFMA = 64 FLOP/LDS-byte (2x the 64x64/wave
// config) — LDS-BW amortization, the lever the m201 template exploits.
// LDS 128KB: staging A 3x16KB @0, B 3x16KB @49152B; epilogue C key tile 256x256 u16.
// K-loop: round-8 proven skeleton — STAGE(kt+1), counted vmcnt(8), raw barrier.
#define AS1(p) ((const __attribute__((address_space(1))) void*)(p))
#define AS3(p) ((__attribute__((address_space(3))) void*)(p))

__global__ __launch_bounds__(256) void k_gemm(const ushort_t* __restrict__ FFbf,
                                              ushort_t* __restrict__ Cs,
                                              ushort_t* __restrict__ Gmax,
                                              int cbase) {
  __shared__ ushort_t smem[65536];  // 128KB
  const int tid = threadIdx.x;
  // XCD-chunked bijective swizzle (256 blocks, 8 XCDs)
  const int swz = ((int)blockIdx.x & 7) * 32 + ((int)blockIdx.x >> 3);
  const int mb = swz >> 3;        // 0..31  (M block: 256 rows)
  const int nb = swz & 7;         // 0..7   (N block: 256 cols)
  const int rbase = mb * 256;
  const int cb = cbase + nb * 256;
  const int w = tid >> 6, lane = tid & 63;
  const int wr = w >> 1, wc = w & 1;          // 2x2 wave grid of 128x128
  const int fr = lane & 15, kg = lane >> 4;

  f32x4 acc[8][8];
#pragma unroll
  for (int m = 0; m < 8; ++m)
#pragma unroll
    for (int n = 0; n < 8; ++n) acc[m][n] = (f32x4){0.f, 0.f, 0.f, 0.f};

  // staging: A tile 256x32 u16 (16KB) via 4 gloads, B tile 256x32 via 4 gloads.
  // row-major [256][32] u16 (64B rows); inst i covers rows i*64+(tid>>2), quad tid&3.
#define STAGE(b, kt) do { \
    const ushort_t* ga = FFbf + (size_t)(rbase + (tid >> 2)) * D_FEAT + (kt) * 32 + (tid & 3) * 8; \
    const ushort_t* gb = FFbf + (size_t)(cb + (tid >> 2)) * D_FEAT + (kt) * 32 + (tid & 3) * 8; \
    char* ab = (char*)smem + (b) * 16384; \
    char* bb = (char*)smem + 49152 + (b) * 16384; \
    __builtin_amdgcn_global_load_lds(AS1(ga), AS3(ab + tid * 16), 16, 0, 0); \
    __builtin_amdgcn_global_load_lds(AS1(ga + (size_t)64 * D_FEAT), AS3(ab + 4096 + tid * 16), 16, 0, 0); \
    __builtin_amdgcn_global_load_lds(AS1(ga + (size_t)128 * D_FEAT), AS3(ab + 8192 + tid * 16), 16, 0, 0); \
    __builtin_amdgcn_global_load_lds(AS1(ga + (size_t)192 * D_FEAT), AS3(ab + 12288 + tid * 16), 16, 0, 0); \
    __builtin_amdgcn_global_load_lds(AS1(gb), AS3(bb + tid * 16), 16, 0, 0); \
    __builtin_amdgcn_global_load_lds(AS1(gb + (size_t)64 * D_FEAT), AS3(bb + 4096 + tid * 16), 16, 0, 0); \
    __builtin_amdgcn_global_load_lds(AS1(gb + (size_t)128 * D_FEAT), AS3(bb + 8192 + tid * 16), 16, 0, 0); \
    __builtin_amdgcn_global_load_lds(AS1(gb + (size_t)192 * D_FEAT), AS3(bb + 12288 + tid * 16), 16, 0, 0); \
  } while (0)

#define COMPUTE(b) do { \
    bf16x8 af[8], bfr[8]; \
    _Pragma("unroll") \
    for (int m = 0; m < 8; ++m) \
      af[m] = *(const bf16x8*)&smem[(b) * 8192 + (wr * 128 + m * 16 + fr) * 32 + kg * 8]; \
    _Pragma("unroll") \
    for (int n = 0; n < 8; ++n) \
      bfr[n] = *(const bf16x8*)&smem[24576 + (b) * 8192 + (wc * 128 + n * 16 + fr) * 32 + kg * 8]; \
    __builtin_amdgcn_s_setprio(1); \
    _Pragma("unroll") \
    for (int m = 0; m < 8; ++m) \
      _Pragma("unroll") \
      for (int n = 0; n < 8; ++n) \
        acc[m][n] = __builtin_amdgcn_mfma_f32_16x16x32_bf16(af[m], bfr[n], acc[m][n], 0, 0, 0); \
    __builtin_amdgcn_s_setprio(0); \
  } while (0)

#define KSTEP(bR, bS, kt) do { \
    if ((kt) + 1 < 24) { \
      STAGE(bS, (kt) + 1); \
      asm volatile("s_waitcnt vmcnt(8)" ::: "memory"); \
    } else { \
      asm volatile("s_waitcnt vmcnt(0)" ::: "memory"); \
    } \
    __builtin_amdgcn_s_barrier(); \
    __builtin_amdgcn_sched_barrier(0); \
    COMPUTE(bR); \
  } while (0)

  STAGE(0, 0);
  for (int kb = 0; kb < 24; kb += 3) {
    KSTEP(0, 1, kb);
    KSTEP(1, 2, kb + 1);
    KSTEP(2, 0, kb + 2);
  }
#undef KSTEP
#undef COMPUTE
#undef STAGE

  // epilogue: keys -> LDS [256][256] u16 (full 128KB), then coalesced stores + Gmax
  __syncthreads();
#pragma unroll
  for (int m = 0; m < 8; ++m)
#pragma unroll
    for (int n = 0; n < 8; ++n)
#pragma unroll
      for (int r = 0; r < 4; ++r)
        smem[(wr * 128 + m * 16 + kg * 4 + r) * 256 + wc * 128 + n * 16 + fr] = f2key(acc[m][n][r]);
  __syncthreads();
#pragma unroll
  for (int i = 0; i < 32; ++i) {
    const int off = i * 4096 + tid * 16;       // byte offset in 128KB C tile
    const int row = off >> 9;                  // 512B per tile row (256 u16)
    const int colb = off & 511;
    const u16x8 v = *(const u16x8*)((const char*)smem + off);
    *(u16x8*)((char*)Cs + (size_t)(rbase + row) * (CHUNK * 2) + (size_t)nb * 512 + colb) = v;
  }
  // group-of-8 column maxes -> Gmax[8192][256] (chunk-local groups); thread = row
  {
#pragma unroll
    for (int gg = 0; gg < 4; ++gg) {
      u16x8 gmv;
#pragma unroll
      for (int g2 = 0; g2 < 8; ++g2) {
        const u16x8 grp = *(const u16x8*)&smem[tid * 256 + (gg * 8 + g2) * 8];
        unsigned mx = 0;
#pragma unroll
        for (int j = 0; j < 8; ++j) mx = max(mx, (unsigned)(ushort_t)grp[j]);
        gmv[g2] = (ushort_t)mx;
      }
      *(u16x8*)&Gmax[(size_t)(rbase + tid) * 256 + nb * 32 + gg * 8] = gmv;
    }
  }
}

// ---------- kernel 3: exact per-row top-16 from Gmax + winning-group gather ----------
__global__ __launch_bounds__(256) void k_sel(const ushort_t* __restrict__ Cs,
                                             const ushort_t* __restrict__ Gmax,
                                             int chunk,
                                             float* __restrict__ pd, int* __restrict__ pi) {
  const int tid = threadIdx.x;
  const int lane = tid & 63;
  const int row = blockIdx.x * 4 + (tid >> 6);
  const ushort_t* src = Cs + (size_t)row * CHUNK;

  // phase 1: top-16 groups from precomputed group maxes
  const u16x4 gm = *(const u16x4*)&Gmax[(size_t)row * 256 + lane * 4];
  unsigned cur[4];
#pragma unroll
  for (int k = 0; k < 4; ++k)
    cur[k] = (((unsigned)(ushort_t)gm[k]) << 16) | (unsigned)(lane * 4 + k);
  unsigned keep = 0;
#pragma unroll
  for (int r = 0; r < 16; ++r) {
    unsigned m = max(max(cur[0], cur[1]), max(cur[2], cur[3]));
    m = wave_max_u32(m);
    if (lane == r) keep = m;
    const unsigned gid = m & 0xFFu;
    if (lane == (int)(gid >> 2)) {
      const int sl = (int)(gid & 3u);
#pragma unroll
      for (int k = 0; k < 4; ++k)
        if (k == sl) cur[k] = 0;
    }
  }
  // phase 2: gather 16 winning groups (128 elems), extract exact top-16
  const unsigned gid2 = keep & 0xFFu;  // valid for lanes 0..15
  unsigned E[8];
  if (lane < 16) {
    const u16x8 g = *(const u16x8*)&src[gid2 * 8];
#pragma unroll
    for (int j = 0; j < 8; ++j)
      E[j] = (((unsigned)(ushort_t)g[j]) << 16) | (gid2 * 8 + (unsigned)j);
  } else {
#pragma unroll
    for (int j = 0; j < 8; ++j) E[j] = 0;
  }
  unsigned keep2 = 0;
#pragma unroll
  for (int r = 0; r < 16; ++r) {
    unsigned m = E[0];
#pragma unroll
    for (int j = 1; j < 8; ++j) m = max(m, E[j]);
    m = wave_max_u32(m);
    if (lane == r) keep2 = m;
    const unsigned col = m & 0xFFFFu;
    const bool mine = (lane < 16) && ((col >> 3) == gid2);
    const int sl = (int)(col & 7u);
#pragma unroll
    for (int j = 0; j < 8; ++j)
      if (mine && j == sl) E[j] = 0;
  }
  if (lane < 16) {
    pd[((size_t)row * NCHUNK + chunk) * 16 + lane] = key2f(keep2 >> 16);
    pi[((size_t)row * NCHUNK + chunk) * 16 + lane] = chunk * CHUNK + (int)(keep2 & 0xFFFFu);
  }
}

// ---------- kernel 4: exact fp32 rescore, one wave per row (also zeroes cnt) ----------
__global__ __launch_bounds__(256) void k_rescore(const float* __restrict__ FF,
                                                 const float* __restrict__ rn,
                                                 const float* __restrict__ sqv,
                                                 const float* __restrict__ pd,
                                                 const int* __restrict__ pi,
                                                 float* __restrict__ tv, int* __restrict__ tj,
                                                 int* __restrict__ cnt) {
  const int tid = threadIdx.x;
  const int lane = tid & 63;
  const int row = blockIdx.x * 4 + (tid >> 6);
  if (lane == 0) cnt[row] = 0;   // scatter's counters; scatter launches after us

  // phase A: top-16 of the 64 chunk candidates by bf16 key (branchless extract)
  const float pdv = pd[(size_t)row * 64 + lane];
  const int myj = pi[(size_t)row * 64 + lane];
  unsigned cur = (((unsigned)f2key(pdv)) << 16) | (unsigned)lane;
  int selj = 0;  // lanes 0..15: j of the r-th selected candidate
#pragma unroll
  for (int r = 0; r < 16; ++r) {
    const unsigned m = wave_max_u32(cur);
    const int wln = (int)(m & 63u);
    const int jw = __shfl(myj, wln, 64);
    if (lane == r) selj = jw;
    if (lane == wln) cur = 0;
  }

  // phase B: exact fp32 dots, full-wave per candidate
  const float si = rn[row];
  const float sqi = sqv[row];
  const float* fi = FF + (size_t)row * D_FEAT;
  float4 a0 = *(const float4*)&fi[lane * 4];
  float4 a1 = *(const float4*)&fi[256 + lane * 4];
  float4 a2 = *(const float4*)&fi[512 + lane * 4];
  a0.x *= si; a0.y *= si; a0.z *= si; a0.w *= si;
  a1.x *= si; a1.y *= si; a1.z *= si; a1.w *= si;
  a2.x *= si; a2.y *= si; a2.z *= si; a2.w *= si;

  float dsc_l = 0.f, dvl_l = 0.f; int j_l = 0;
#pragma unroll 8
  for (int c = 0; c < 16; ++c) {
    const int j = __shfl(selj, c, 64);
    const float sj = rn[j];
    const float* fj = FF + (size_t)j * D_FEAT;
    const float4 b0 = *(const float4*)&fj[lane * 4];
    const float4 b1 = *(const float4*)&fj[256 + lane * 4];
    const float4 b2 = *(const float4*)&fj[512 + lane * 4];
    float acc = 0.f;
    acc = fmaf(a0.x, b0.x * sj, acc); acc = fmaf(a0.y, b0.y * sj, acc);
    acc = fmaf(a0.z, b0.z * sj, acc); acc = fmaf(a0.w, b0.w * sj, acc);
    acc = fmaf(a1.x, b1.x * sj, acc); acc = fmaf(a1.y, b1.y * sj, acc);
    acc = fmaf(a1.z, b1.z * sj, acc); acc = fmaf(a1.w, b1.w * sj, acc);
    acc = fmaf(a2.x, b2.x * sj, acc); acc = fmaf(a2.y, b2.y * sj, acc);
    acc = fmaf(a2.z, b2.z * sj, acc); acc = fmaf(a2.w, b2.w * sj, acc);
#pragma unroll
    for (int m = 32; m > 0; m >>= 1) acc += __shfl_xor(acc, m, 64);
    if (lane == c) {
      const float sqj = sqv[j];
      j_l = j;
      dsc_l = acc - 0.5f * sqj;  // exactly monotone with the exp comparator
      dvl_l = expf(-0.5f * (sqi + sqj - 2.f * acc));
    }
  }

  // phase C: top-10 of 16 by exact dsc (branchless extract), write tv/tj
  unsigned fk = 0;
  if (lane < 16) {
    const unsigned u = f2u(dsc_l);
    fk = u ^ ((u >> 31) ? 0xFFFFFFFFu : 0x80000000u);
  }
#pragma unroll
  for (int s = 0; s < 10; ++s) {
    const unsigned m = wave_max_u32(fk);
    const unsigned long long bal = __ballot(fk == m);
    const int wln = __ffsll((unsigned long long)bal) - 1;
    const float tvv = __shfl(dvl_l, wln, 64);
    const int tjj = __shfl(j_l, wln, 64);
    if (lane == s) {
      tv[(size_t)row * KNN + s] = tvv;
      tj[(size_t)row * KNN + s] = tjj;
    }
    if (lane == wln) fk = 0;
  }
}

// ---------- kernel 5: scatter both edge directions ----------
__global__ void k_scatter(const float* __restrict__ tv, const int* __restrict__ tj,
                          int* __restrict__ cnt, int* __restrict__ nbrJ,
                          float* __restrict__ nbrW) {
  const int e = blockIdx.x * blockDim.x + threadIdx.x;
  if (e >= N_TOK * KNN) return;
  const int i = e / KNN;
  const int j = tj[e];
  if (j == i) return;
  const float w = 0.5f * tv[e];
  const int p = atomicAdd(&cnt[i], 1);
  if (p < CAP) { nbrJ[(size_t)i * CAP + p] = j; nbrW[(size_t)i * CAP + p] = w; }
  const int q = atomicAdd(&cnt[j], 1);
  if (q < CAP) { nbrJ[(size_t)j * CAP + q] = i; nbrW[(size_t)j * CAP + q] = w; }
}

// ---------- kernel 6: degree + rsqrt ----------
__global__ void k_degree(const int* __restrict__ cnt, const float* __restrict__ nbrW,
                         float* __restrict__ Dv) {
  const int r = blockIdx.x * 4 + (threadIdx.x >> 6);
  const int lane = threadIdx.x & 63;
  const int c = min(cnt[r], CAP);
  float s = 0.f;
  for (int m = lane; m < c; m += 64) s += nbrW[(size_t)r * CAP + m];
  for (int m = 32; m > 0; m >>= 1) s += __shfl_xor(s, m, 64);
  if (lane == 0) Dv[r] = (s > 0.f) ? rsqrtf(s) : 0.f;
}

// ---------- kernel 7: gPsi ----------
__global__ __launch_bounds__(256) void k_gpsi(const float* __restrict__ Psi,
                                              const int* __restrict__ cnt,
                                              const int* __restrict__ nbrJ,
                                              const float* __restrict__ nbrW,
                                              const float* __restrict__ Dv,
                                              float* __restrict__ gP) {
  const int i = blockIdx.x;
  const int tid = threadIdx.x;
  __shared__ int sJ[CAP];
  __shared__ float sW[CAP];
  const int c = min(cnt[i], CAP);
  if (tid < c) {
    const int j = nbrJ[(size_t)i * CAP + tid];
    sJ[tid] = j;
    sW[tid] = nbrW[(size_t)i * CAP + tid] * Dv[j];
  }
  __syncthreads();
  float acc = 0.f;
  for (int m = 0; m < c; ++m) acc += sW[m] * Psi[(size_t)sJ[m] * K_EIG + tid];
  gP[(size_t)i * K_EIG + tid] = acc * Dv[i];
}

// ---------- kernel 8a: split-K partials of R = Psi^T @ gPsi ----------
__global__ __launch_bounds__(256) void k_Rpart(const float* __restrict__ Psi,
                                               const float* __restrict__ gP,
                                               float* __restrict__ Rp) {
  __shared__ float sP[64][68];
  __shared__ float sG[64][68];
  const int tid = threadIdx.x;
  const int ks = blockIdx.x >> 4;
  const int tile = blockIdx.x & 15;
  const int at = (tile >> 2) * 64;
  const int bt = (tile & 3) * 64;
  const int a4 = (tid & 15) * 4;
  const int b4 = (tid >> 4) * 4;
  const int lr = tid >> 2;

  float acc[4][4];
#pragma unroll
  for (int i = 0; i < 4; ++i)
#pragma unroll
    for (int j = 0; j < 4; ++j) acc[i][j] = 0.f;

  for (int rt = 0; rt < 8; ++rt) {
    const int r0 = ks * 512 + rt * 64;
    __syncthreads();
#pragma unroll
    for (int q = 0; q < 4; ++q) {
      const int seg = (tid & 3) + q * 4;
      *(float4*)&sP[lr][seg * 4] = *(const float4*)&Psi[(size_t)(r0 + lr) * K_EIG + at + seg * 4];
      *(float4*)&sG[lr][seg * 4] = *(const float4*)&gP[(size_t)(r0 + lr) * K_EIG + bt + seg * 4];
    }
    __syncthreads();
#pragma unroll 4
    for (int r = 0; r < 64; ++r) {
      const float4 pa = *(const float4*)&sP[r][a4];
      const float4 pg = *(const float4*)&sG[r][b4];
      acc[0][0] = fmaf(pa.x, pg.x, acc[0][0]); acc[0][1] = fmaf(pa.x, pg.y, acc[0][1]);
      acc[0][2] = fmaf(pa.x, pg.z, acc[0][2]); acc[0][3] = fmaf(pa.x, pg.w, acc[0][3]);
      acc[1][0] = fmaf(pa.y, pg.x, acc[1][0]); acc[1][1] = fmaf(pa.y, pg.y, acc[1][1]);
      acc[1][2] = fmaf(pa.y, pg.z, acc[1][2]); acc[1][3] = fmaf(pa.y, pg.w, acc[1][3]);
      acc[2][0] = fmaf(pa.z, pg.x, acc[2][0]); acc[2][1] = fmaf(pa.z, pg.y, acc[2][1]);
      acc[2][2] = fmaf(pa.z, pg.z, acc[2][2]); acc[2][3] = fmaf(pa.z, pg.w, acc[2][3]);
      acc[3][0] = fmaf(pa.w, pg.x, acc[3][0]); acc[3][1] = fmaf(pa.w, pg.y, acc[3][1]);
      acc[3][2] = fmaf(pa.w, pg.z, acc[3][2]); acc[3][3] = fmaf(pa.w, pg.w, acc[3][3]);
    }
  }
#pragma unroll
  for (int i = 0; i < 4; ++i) {
    float4 o; o.x = acc[i][0]; o.y = acc[i][1]; o.z = acc[i][2]; o.w = acc[i][3];
    *(float4*)&Rp[(size_t)ks * (K_EIG * K_EIG) + (size_t)(at + a4 + i) * K_EIG + bt + b4] = o;
  }
}

// ---------- kernel 8b: reduce 16 slices + partial trace/triu sums ----------
__global__ __launch_bounds__(256) void k_Rred(const float* __restrict__ Rp,
                                              double* __restrict__ part) {
  const int tid = threadIdx.x;
  const int e0 = blockIdx.x * 1024 + tid * 4;
  float4 s = {0.f, 0.f, 0.f, 0.f};
  for (int ks = 0; ks < 16; ++ks) {
    const float4 v = *(const float4*)&Rp[(size_t)ks * (K_EIG * K_EIG) + e0];
    s.x += v.x; s.y += v.y; s.z += v.z; s.w += v.w;
  }
  const float sc = (10.f / 8192.f) * (10.f / 8192.f);
  double tl = 0.0, rg = 0.0;
#pragma unroll
  for (int j = 0; j < 4; ++j) {
    const int e = e0 + j;
    const int a = e >> 8, b = e & 255;
    const double v = (double)(((const float*)&s)[j] * sc);
    if (a == b) tl += v;
    else if (b > a) rg += v * v;
  }
  __shared__ double st[256], sr[256];
  st[tid] = tl; sr[tid] = rg;
  __syncthreads();
  for (int w = 128; w > 0; w >>= 1) {
    if (tid < w) { st[tid] += st[tid + w]; sr[tid] += sr[tid + w]; }
    __syncthreads();
  }
  if (tid == 0) { part[blockIdx.x] = st[0]; part[64 + blockIdx.x] = sr[0]; }
}

// ---------- kernel 9: fold 64 block partials -> 2 outputs ----------
__global__ void k_final2(const double* __restrict__ part, float* __restrict__ out) {
  const int lane = threadIdx.x;
  double tl = part[lane];
  double rg = part[64 + lane];
  for (int m = 32; m > 0; m >>= 1) {
    tl += __shfl_xor(tl, m, 64);
    rg += __shfl_xor(rg, m, 64);
  }
  if (lane == 0) {
    out[0] = (float)(-tl);
    out[1] = (float)(rg * 0.05);
  }
}

extern "C" void kernel_launch(void* const* d_in, const int* in_sizes, int n_in,
                              void* d_out, int out_size, void* d_ws, size_t ws_size,
                              hipStream_t stream) {
  const float* FF = (const float*)d_in[0];
  const float* Psi = (const float*)d_in[1];
  float* out = (float*)d_out;
  float* ws = (float*)d_ws;

  size_t o = 0;
  ushort_t* FFbf = (ushort_t*)(ws + o); o += (size_t)N_TOK * D_FEAT / 2;
  float* rn  = ws + o; o += N_TOK;
  float* sqv = ws + o; o += N_TOK;
  float* pd  = ws + o; o += (size_t)N_TOK * NCHUNK * 16;
  int*   pi  = (int*)(ws + o); o += (size_t)N_TOK * NCHUNK * 16;
  float* tv  = ws + o; o += (size_t)N_TOK * KNN;
  int*   tj  = (int*)(ws + o); o += (size_t)N_TOK * KNN;
  int*   cnt = (int*)(ws + o); o += N_TOK;
  double* part = (double*)(ws + o); o += 256;  // 128 doubles
  ushort_t* Gmax = (ushort_t*)(ws + o); o += (size_t)N_TOK * 256 / 2;  // 4 MB
  // region X (32 MB, size of Cs): Cs dead after k_rescore, then reused:
  //   nbrJ (8MB) | nbrW (8MB) | Dv (32KB) | gP (8MB) | Rp (4MB at +25MB)
  char* X = (char*)(ws + o);
  ushort_t* Cs = (ushort_t*)X;
  int*   nbrJ = (int*)X;
  float* nbrW = (float*)(X + (size_t)N_TOK * CAP * 4);
  float* Dv   = (float*)(X + 2 * (size_t)N_TOK * CAP * 4);
  float* gP   = (float*)(X + 2 * (size_t)N_TOK * CAP * 4 + (size_t)N_TOK * 4);
  float* Rp   = (float*)(X + 25ull * 1024 * 1024);

  k_norm<<<N_TOK, 192, 0, stream>>>(FF, FFbf, rn, sqv);
  for (int c = 0; c < NCHUNK; ++c) {
    k_gemm<<<(N_TOK / 256) * (CHUNK / 256), 256, 0, stream>>>(FFbf, Cs, Gmax, c * CHUNK);
    k_sel<<<N_TOK / 4, 256, 0, stream>>>(Cs, Gmax, c, pd, pi);
  }
  k_rescore<<<N_TOK / 4, 256, 0, stream>>>(FF, rn, sqv, pd, pi, tv, tj, cnt);
  k_scatter<<<(N_TOK * KNN + 255) / 256, 256, 0, stream>>>(tv, tj, cnt, nbrJ, nbrW);
  k_degree<<<N_TOK / 4, 256, 0, stream>>>(cnt, nbrW, Dv);
  k_gpsi<<<N_TOK, 256, 0, stream>>>(Psi, cnt, nbrJ, nbrW, Dv, gP);
  k_Rpart<<<256, 256, 0, stream>>>(Psi, gP, Rp);
  k_Rred<<<64, 256, 0, stream>>>(Rp, part);
  k_final2<<<1, 64, 0, stream>>>(part, out);
}

// Round 14
// 340.033 us; speedup vs baseline: 1.1437x; 1.1437x over previous
//
#include <hip/hip_runtime.h>
#include <math.h>

#define N_TOK 8192
#define D_FEAT 768
#define K_EIG 256
#define KNN 10
#define CAP 256
#define NCHUNK 4
#define CHUNK 2048

typedef unsigned short ushort_t;
typedef float f32x4 __attribute__((ext_vector_type(4)));
typedef short bf16x8 __attribute__((ext_vector_type(8)));
typedef unsigned short u16x8 __attribute__((ext_vector_type(8)));
typedef unsigned short u16x4 __attribute__((ext_vector_type(4)));

__device__ inline float u2f(unsigned u) { union { unsigned u; float f; } c; c.u = u; return c.f; }
__device__ inline unsigned f2u(float f) { union { unsigned u; float f; } c; c.f = f; return c.u; }
__device__ inline ushort_t f2bf_rne(float f) {
  const unsigned u = f2u(f);
  return (ushort_t)((u + 0x7fffu + ((u >> 16) & 1u)) >> 16);
}
// monotone u16 key from f32 (truncate to bf16, flip for total order)
__device__ inline ushort_t f2key(float f) {
  const unsigned h = f2u(f) >> 16;
  return (ushort_t)((h & 0x8000u) ? (h ^ 0xFFFFu) : (h | 0x8000u));
}
__device__ inline float key2f(unsigned k) {
  const unsigned h = (k & 0x8000u) ? (k ^ 0x8000u) : (k ^ 0xFFFFu);
  return u2f(h << 16);
}
__device__ inline unsigned wave_max_u32(unsigned m) {
#pragma unroll
  for (int s = 1; s < 64; s <<= 1) m = max(m, (unsigned)__shfl_xor((int)m, s, 64));
  return m;
}

// ---------- kernel 1: row stats + bf16 normalized copy (vectorized) ----------
__global__ __launch_bounds__(192) void k_norm(const float* __restrict__ FF,
                                              ushort_t* __restrict__ FFbf,
                                              float* __restrict__ rn,
                                              float* __restrict__ sqv) {
  const int row = blockIdx.x;
  const int tid = threadIdx.x;
  const float4 v = *(const float4*)&FF[(size_t)row * D_FEAT + tid * 4];
  float s = v.x * v.x + v.y * v.y + v.z * v.z + v.w * v.w;
  __shared__ float red[3];
  for (int m = 32; m > 0; m >>= 1) s += __shfl_xor(s, m, 64);
  if ((tid & 63) == 0) red[tid >> 6] = s;
  __syncthreads();
  const float tot = red[0] + red[1] + red[2];
  const float scale = 1.f / fmaxf(sqrtf(tot), 1e-12f);
  float4 w;
  w.x = v.x * scale; w.y = v.y * scale; w.z = v.z * scale; w.w = v.w * scale;
  float s2 = w.x * w.x + w.y * w.y + w.z * w.z + w.w * w.w;
  u16x4 o;
  o[0] = f2bf_rne(w.x); o[1] = f2bf_rne(w.y); o[2] = f2bf_rne(w.z); o[3] = f2bf_rne(w.w);
  *(u16x4*)&FFbf[(size_t)row * D_FEAT + tid * 4] = o;
  for (int m = 32; m > 0; m >>= 1) s2 += __shfl_xor(s2, m, 64);
  __syncthreads();
  if ((tid & 63) == 0) red[tid >> 6] = s2;
  __syncthreads();
  if (tid == 0) { sqv[row] = red[0] + red[1] + red[2]; rn[row] = scale; }
}

// ---------- kernel 2: 256x256-tile GEMM, 8 waves x (128x64)/wave, BK=64, swizzled LDS ----------
// 512 threads = 8 waves (2M x 4N). Per-wave per K-step: 64 MFMA (1.05 MFLOP) vs
// 24 ds_read_b128 (24 KB) = 43.7 FLOP/LDS-byte > 31.8 balance -> MFMA-bound.
// acc[8][4] = 128 VGPR -> 2 waves/SIMD. LDS 128KB: A dbuf 2x32KB @0, B 2x32KB @64KB.
// Swizzle (rule #21, both-sides): write side stores LDS[r][d] = G[r][d^(r&7)]
// (linear LDS dest + inverse-swizzled per-lane GLOBAL source); read side fetches
// G[r][s] from LDS slot s^(r&7), s = kk*4+kg (FULL 3-bit slot XOR — round-13's bug
// was XOR-ing only kg). All fragment rows are == fr (mod 8): wr*128, m*16, wc*64,
// n*16 all == 0 mod 8, so r&7 == fr&7 at read time.
#define AS1(p) ((const __attribute__((address_space(1))) void*)(p))
#define AS3(p) ((__attribute__((address_space(3))) void*)(p))

__global__ __launch_bounds__(512) void k_gemm(const ushort_t* __restrict__ FFbf,
                                              ushort_t* __restrict__ Cs,
                                              ushort_t* __restrict__ Gmax,
                                              int cbase) {
  __shared__ ushort_t smem[65536];  // 128KB
  const int tid = threadIdx.x;
  // XCD-chunked bijective swizzle (256 blocks, 8 XCDs)
  const int swz = ((int)blockIdx.x & 7) * 32 + ((int)blockIdx.x >> 3);
  const int mb = swz >> 3;        // 0..31  (M block: 256 rows)
  const int nb = swz & 7;         // 0..7   (N block: 256 cols)
  const int rbase = mb * 256;
  const int cb = cbase + nb * 256;
  const int w = tid >> 6, lane = tid & 63;
  const int wr = w >> 2;          // 0..1  M: rows wr*128..
  const int wc = w & 3;           // 0..3  N: cols wc*64..
  const int fr = lane & 15, kg = lane >> 4;
  const int h8 = fr & 7;
  const int slot0 = ((kg ^ h8) * 16);        // kk=0 slot byte offset (slot = kg^h8)
  const int slot1 = slot0 ^ 64;              // kk=1: (4+kg)^h8 = (kg^h8)^4 -> +-64B
  const int srow = tid >> 3;                 // staging row within 64-row stripe
  const int scol = (((tid & 7) ^ ((tid >> 3) & 7)) * 8);  // inverse-swizzled src col (u16)

  f32x4 acc[8][4];
#pragma unroll
  for (int m = 0; m < 8; ++m)
#pragma unroll
    for (int n = 0; n < 4; ++n) acc[m][n] = (f32x4){0.f, 0.f, 0.f, 0.f};

  // stage one K-tile (BK=64): A 256x64 u16 (32KB, 4 gloads) + B 32KB (4 gloads)
#define STAGE(b, kt) do { \
    const ushort_t* ga = FFbf + (size_t)(rbase + srow) * D_FEAT + (kt) * 64 + scol; \
    const ushort_t* gb = FFbf + (size_t)(cb + srow) * D_FEAT + (kt) * 64 + scol; \
    char* ab = (char*)smem + (b) * 32768; \
    char* bb = (char*)smem + 65536 + (b) * 32768; \
    __builtin_amdgcn_global_load_lds(AS1(ga), AS3(ab + tid * 16), 16, 0, 0); \
    __builtin_amdgcn_global_load_lds(AS1(ga + (size_t)64 * D_FEAT), AS3(ab + 8192 + tid * 16), 16, 0, 0); \
    __builtin_amdgcn_global_load_lds(AS1(ga + (size_t)128 * D_FEAT), AS3(ab + 16384 + tid * 16), 16, 0, 0); \
    __builtin_amdgcn_global_load_lds(AS1(ga + (size_t)192 * D_FEAT), AS3(ab + 24576 + tid * 16), 16, 0, 0); \
    __builtin_amdgcn_global_load_lds(AS1(gb), AS3(bb + tid * 16), 16, 0, 0); \
    __builtin_amdgcn_global_load_lds(AS1(gb + (size_t)64 * D_FEAT), AS3(bb + 8192 + tid * 16), 16, 0, 0); \
    __builtin_amdgcn_global_load_lds(AS1(gb + (size_t)128 * D_FEAT), AS3(bb + 16384 + tid * 16), 16, 0, 0); \
    __builtin_amdgcn_global_load_lds(AS1(gb + (size_t)192 * D_FEAT), AS3(bb + 24576 + tid * 16), 16, 0, 0); \
  } while (0)

  STAGE(0, 0);
  for (int t = 0; t < 12; ++t) {
    const int cur = t & 1;
    if (t + 1 < 12) {
      STAGE(cur ^ 1, t + 1);
      asm volatile("s_waitcnt vmcnt(8)" ::: "memory");
    } else {
      asm volatile("s_waitcnt vmcnt(0)" ::: "memory");
    }
    __builtin_amdgcn_s_barrier();
    __builtin_amdgcn_sched_barrier(0);
    {
      const char* abuf = (const char*)smem + cur * 32768;
      const char* bbuf = (const char*)smem + 65536 + cur * 32768;
      // B frags: n=0..3, kk=0..1 (8 b128), swizzled read addr
      bf16x8 bfr[4][2];
#pragma unroll
      for (int n = 0; n < 4; ++n) {
        const int brow = (wc * 64 + n * 16 + fr) * 128;
        bfr[n][0] = *(const bf16x8*)(bbuf + brow + slot0);
        bfr[n][1] = *(const bf16x8*)(bbuf + brow + slot1);
      }
      __builtin_amdgcn_s_setprio(1);
#pragma unroll
      for (int m = 0; m < 8; ++m) {
        const int arow = (wr * 128 + m * 16 + fr) * 128;
        const bf16x8 af0 = *(const bf16x8*)(abuf + arow + slot0);
        const bf16x8 af1 = *(const bf16x8*)(abuf + arow + slot1);
#pragma unroll
        for (int n = 0; n < 4; ++n) {
          acc[m][n] = __builtin_amdgcn_mfma_f32_16x16x32_bf16(af0, bfr[n][0], acc[m][n], 0, 0, 0);
          acc[m][n] = __builtin_amdgcn_mfma_f32_16x16x32_bf16(af1, bfr[n][1], acc[m][n], 0, 0, 0);
        }
      }
      __builtin_amdgcn_s_setprio(0);
    }
    __builtin_amdgcn_s_barrier();
  }
#undef STAGE

  // epilogue: keys -> LDS [256][256] u16 (128KB reuse), coalesced stores + Gmax
#pragma unroll
  for (int m = 0; m < 8; ++m)
#pragma unroll
    for (int n = 0; n < 4; ++n)
#pragma unroll
      for (int r = 0; r < 4; ++r)
        smem[(wr * 128 + m * 16 + kg * 4 + r) * 256 + wc * 64 + n * 16 + fr] = f2key(acc[m][n][r]);
  __syncthreads();
#pragma unroll
  for (int i = 0; i < 16; ++i) {
    const int off = i * 8192 + tid * 16;       // byte offset in 128KB C tile
    const int row = off >> 9;                  // 512B per tile row (256 u16)
    const int colb = off & 511;
    const u16x8 v = *(const u16x8*)((const char*)smem + off);
    *(u16x8*)((char*)Cs + (size_t)(rbase + row) * (CHUNK * 2) + (size_t)nb * 512 + colb) = v;
  }
  // group-of-8 column maxes -> Gmax[8192][256] (chunk-local groups)
  {
    const int r2 = tid >> 1;                   // 0..255
    const int gh = (tid & 1) * 16;             // 16 groups per thread-half
#pragma unroll
    for (int gg = 0; gg < 2; ++gg) {
      u16x8 gmv;
#pragma unroll
      for (int g2 = 0; g2 < 8; ++g2) {
        const u16x8 grp = *(const u16x8*)&smem[r2 * 256 + (gh + gg * 8 + g2) * 8];
        unsigned mx = 0;
#pragma unroll
        for (int j = 0; j < 8; ++j) mx = max(mx, (unsigned)(ushort_t)grp[j]);
        gmv[g2] = (ushort_t)mx;
      }
      *(u16x8*)&Gmax[(size_t)(rbase + r2) * 256 + nb * 32 + gh + gg * 8] = gmv;
    }
  }
}

// ---------- kernel 3: exact per-row top-16 from Gmax + winning-group gather ----------
__global__ __launch_bounds__(256) void k_sel(const ushort_t* __restrict__ Cs,
                                             const ushort_t* __restrict__ Gmax,
                                             int chunk,
                                             float* __restrict__ pd, int* __restrict__ pi) {
  const int tid = threadIdx.x;
  const int lane = tid & 63;
  const int row = blockIdx.x * 4 + (tid >> 6);
  const ushort_t* src = Cs + (size_t)row * CHUNK;

  // phase 1: top-16 groups from precomputed group maxes
  const u16x4 gm = *(const u16x4*)&Gmax[(size_t)row * 256 + lane * 4];
  unsigned cur[4];
#pragma unroll
  for (int k = 0; k < 4; ++k)
    cur[k] = (((unsigned)(ushort_t)gm[k]) << 16) | (unsigned)(lane * 4 + k);
  unsigned keep = 0;
#pragma unroll
  for (int r = 0; r < 16; ++r) {
    unsigned m = max(max(cur[0], cur[1]), max(cur[2], cur[3]));
    m = wave_max_u32(m);
    if (lane == r) keep = m;
    const unsigned gid = m & 0xFFu;
    if (lane == (int)(gid >> 2)) {
      const int sl = (int)(gid & 3u);
#pragma unroll
      for (int k = 0; k < 4; ++k)
        if (k == sl) cur[k] = 0;
    }
  }
  // phase 2: gather 16 winning groups (128 elems), extract exact top-16
  const unsigned gid2 = keep & 0xFFu;  // valid for lanes 0..15
  unsigned E[8];
  if (lane < 16) {
    const u16x8 g = *(const u16x8*)&src[gid2 * 8];
#pragma unroll
    for (int j = 0; j < 8; ++j)
      E[j] = (((unsigned)(ushort_t)g[j]) << 16) | (gid2 * 8 + (unsigned)j);
  } else {
#pragma unroll
    for (int j = 0; j < 8; ++j) E[j] = 0;
  }
  unsigned keep2 = 0;
#pragma unroll
  for (int r = 0; r < 16; ++r) {
    unsigned m = E[0];
#pragma unroll
    for (int j = 1; j < 8; ++j) m = max(m, E[j]);
    m = wave_max_u32(m);
    if (lane == r) keep2 = m;
    const unsigned col = m & 0xFFFFu;
    const bool mine = (lane < 16) && ((col >> 3) == gid2);
    const int sl = (int)(col & 7u);
#pragma unroll
    for (int j = 0; j < 8; ++j)
      if (mine && j == sl) E[j] = 0;
  }
  if (lane < 16) {
    pd[((size_t)row * NCHUNK + chunk) * 16 + lane] = key2f(keep2 >> 16);
    pi[((size_t)row * NCHUNK + chunk) * 16 + lane] = chunk * CHUNK + (int)(keep2 & 0xFFFFu);
  }
}

// ---------- kernel 4: exact fp32 rescore, one wave per row (also zeroes cnt) ----------
__global__ __launch_bounds__(256) void k_rescore(const float* __restrict__ FF,
                                                 const float* __restrict__ rn,
                                                 const float* __restrict__ sqv,
                                                 const float* __restrict__ pd,
                                                 const int* __restrict__ pi,
                                                 float* __restrict__ tv, int* __restrict__ tj,
                                                 int* __restrict__ cnt) {
  const int tid = threadIdx.x;
  const int lane = tid & 63;
  const int row = blockIdx.x * 4 + (tid >> 6);
  if (lane == 0) cnt[row] = 0;   // scatter's counters; scatter launches after us

  // phase A: top-16 of the 64 chunk candidates by bf16 key (branchless extract)
  const float pdv = pd[(size_t)row * 64 + lane];
  const int myj = pi[(size_t)row * 64 + lane];
  unsigned cur = (((unsigned)f2key(pdv)) << 16) | (unsigned)lane;
  int selj = 0;  // lanes 0..15: j of the r-th selected candidate
#pragma unroll
  for (int r = 0; r < 16; ++r) {
    const unsigned m = wave_max_u32(cur);
    const int wln = (int)(m & 63u);
    const int jw = __shfl(myj, wln, 64);
    if (lane == r) selj = jw;
    if (lane == wln) cur = 0;
  }

  // phase B: exact fp32 dots, full-wave per candidate
  const float si = rn[row];
  const float sqi = sqv[row];
  const float* fi = FF + (size_t)row * D_FEAT;
  float4 a0 = *(const float4*)&fi[lane * 4];
  float4 a1 = *(const float4*)&fi[256 + lane * 4];
  float4 a2 = *(const float4*)&fi[512 + lane * 4];
  a0.x *= si; a0.y *= si; a0.z *= si; a0.w *= si;
  a1.x *= si; a1.y *= si; a1.z *= si; a1.w *= si;
  a2.x *= si; a2.y *= si; a2.z *= si; a2.w *= si;

  float dsc_l = 0.f, dvl_l = 0.f; int j_l = 0;
#pragma unroll 8
  for (int c = 0; c < 16; ++c) {
    const int j = __shfl(selj, c, 64);
    const float sj = rn[j];
    const float* fj = FF + (size_t)j * D_FEAT;
    const float4 b0 = *(const float4*)&fj[lane * 4];
    const float4 b1 = *(const float4*)&fj[256 + lane * 4];
    const float4 b2 = *(const float4*)&fj[512 + lane * 4];
    float acc = 0.f;
    acc = fmaf(a0.x, b0.x * sj, acc); acc = fmaf(a0.y, b0.y * sj, acc);
    acc = fmaf(a0.z, b0.z * sj, acc); acc = fmaf(a0.w, b0.w * sj, acc);
    acc = fmaf(a1.x, b1.x * sj, acc); acc = fmaf(a1.y, b1.y * sj, acc);
    acc = fmaf(a1.z, b1.z * sj, acc); acc = fmaf(a1.w, b1.w * sj, acc);
    acc = fmaf(a2.x, b2.x * sj, acc); acc = fmaf(a2.y, b2.y * sj, acc);
    acc = fmaf(a2.z, b2.z * sj, acc); acc = fmaf(a2.w, b2.w * sj, acc);
#pragma unroll
    for (int m = 32; m > 0; m >>= 1) acc += __shfl_xor(acc, m, 64);
    if (lane == c) {
      const float sqj = sqv[j];
      j_l = j;
      dsc_l = acc - 0.5f * sqj;  // exactly monotone with the exp comparator
      dvl_l = expf(-0.5f * (sqi + sqj - 2.f * acc));
    }
  }

  // phase C: top-10 of 16 by exact dsc (branchless extract), write tv/tj
  unsigned fk = 0;
  if (lane < 16) {
    const unsigned u = f2u(dsc_l);
    fk = u ^ ((u >> 31) ? 0xFFFFFFFFu : 0x80000000u);
  }
#pragma unroll
  for (int s = 0; s < 10; ++s) {
    const unsigned m = wave_max_u32(fk);
    const unsigned long long bal = __ballot(fk == m);
    const int wln = __ffsll((unsigned long long)bal) - 1;
    const float tvv = __shfl(dvl_l, wln, 64);
    const int tjj = __shfl(j_l, wln, 64);
    if (lane == s) {
      tv[(size_t)row * KNN + s] = tvv;
      tj[(size_t)row * KNN + s] = tjj;
    }
    if (lane == wln) fk = 0;
  }
}

// ---------- kernel 5: scatter both edge directions ----------
__global__ void k_scatter(const float* __restrict__ tv, const int* __restrict__ tj,
                          int* __restrict__ cnt, int* __restrict__ nbrJ,
                          float* __restrict__ nbrW) {
  const int e = blockIdx.x * blockDim.x + threadIdx.x;
  if (e >= N_TOK * KNN) return;
  const int i = e / KNN;
  const int j = tj[e];
  if (j == i) return;
  const float w = 0.5f * tv[e];
  const int p = atomicAdd(&cnt[i], 1);
  if (p < CAP) { nbrJ[(size_t)i * CAP + p] = j; nbrW[(size_t)i * CAP + p] = w; }
  const int q = atomicAdd(&cnt[j], 1);
  if (q < CAP) { nbrJ[(size_t)j * CAP + q] = i; nbrW[(size_t)j * CAP + q] = w; }
}

// ---------- kernel 6: degree + rsqrt ----------
__global__ void k_degree(const int* __restrict__ cnt, const float* __restrict__ nbrW,
                         float* __restrict__ Dv) {
  const int r = blockIdx.x * 4 + (threadIdx.x >> 6);
  const int lane = threadIdx.x & 63;
  const int c = min(cnt[r], CAP);
  float s = 0.f;
  for (int m = lane; m < c; m += 64) s += nbrW[(size_t)r * CAP + m];
  for (int m = 32; m > 0; m >>= 1) s += __shfl_xor(s, m, 64);
  if (lane == 0) Dv[r] = (s > 0.f) ? rsqrtf(s) : 0.f;
}

// ---------- kernel 7: gPsi ----------
__global__ __launch_bounds__(256) void k_gpsi(const float* __restrict__ Psi,
                                              const int* __restrict__ cnt,
                                              const int* __restrict__ nbrJ,
                                              const float* __restrict__ nbrW,
                                              const float* __restrict__ Dv,
                                              float* __restrict__ gP) {
  const int i = blockIdx.x;
  const int tid = threadIdx.x;
  __shared__ int sJ[CAP];
  __shared__ float sW[CAP];
  const int c = min(cnt[i], CAP);
  if (tid < c) {
    const int j = nbrJ[(size_t)i * CAP + tid];
    sJ[tid] = j;
    sW[tid] = nbrW[(size_t)i * CAP + tid] * Dv[j];
  }
  __syncthreads();
  float acc = 0.f;
  for (int m = 0; m < c; ++m) acc += sW[m] * Psi[(size_t)sJ[m] * K_EIG + tid];
  gP[(size_t)i * K_EIG + tid] = acc * Dv[i];
}

// ---------- kernel 8a: split-K partials of R = Psi^T @ gPsi ----------
__global__ __launch_bounds__(256) void k_Rpart(const float* __restrict__ Psi,
                                               const float* __restrict__ gP,
                                               float* __restrict__ Rp) {
  __shared__ float sP[64][68];
  __shared__ float sG[64][68];
  const int tid = threadIdx.x;
  const int ks = blockIdx.x >> 4;
  const int tile = blockIdx.x & 15;
  const int at = (tile >> 2) * 64;
  const int bt = (tile & 3) * 64;
  const int a4 = (tid & 15) * 4;
  const int b4 = (tid >> 4) * 4;
  const int lr = tid >> 2;

  float acc[4][4];
#pragma unroll
  for (int i = 0; i < 4; ++i)
#pragma unroll
    for (int j = 0; j < 4; ++j) acc[i][j] = 0.f;

  for (int rt = 0; rt < 8; ++rt) {
    const int r0 = ks * 512 + rt * 64;
    __syncthreads();
#pragma unroll
    for (int q = 0; q < 4; ++q) {
      const int seg = (tid & 3) + q * 4;
      *(float4*)&sP[lr][seg * 4] = *(const float4*)&Psi[(size_t)(r0 + lr) * K_EIG + at + seg * 4];
      *(float4*)&sG[lr][seg * 4] = *(const float4*)&gP[(size_t)(r0 + lr) * K_EIG + bt + seg * 4];
    }
    __syncthreads();
#pragma unroll 4
    for (int r = 0; r < 64; ++r) {
      const float4 pa = *(const float4*)&sP[r][a4];
      const float4 pg = *(const float4*)&sG[r][b4];
      acc[0][0] = fmaf(pa.x, pg.x, acc[0][0]); acc[0][1] = fmaf(pa.x, pg.y, acc[0][1]);
      acc[0][2] = fmaf(pa.x, pg.z, acc[0][2]); acc[0][3] = fmaf(pa.x, pg.w, acc[0][3]);
      acc[1][0] = fmaf(pa.y, pg.x, acc[1][0]); acc[1][1] = fmaf(pa.y, pg.y, acc[1][1]);
      acc[1][2] = fmaf(pa.y, pg.z, acc[1][2]); acc[1][3] = fmaf(pa.y, pg.w, acc[1][3]);
      acc[2][0] = fmaf(pa.z, pg.x, acc[2][0]); acc[2][1] = fmaf(pa.z, pg.y, acc[2][1]);
      acc[2][2] = fmaf(pa.z, pg.z, acc[2][2]); acc[2][3] = fmaf(pa.z, pg.w, acc[2][3]);
      acc[3][0] = fmaf(pa.w, pg.x, acc[3][0]); acc[3][1] = fmaf(pa.w, pg.y, acc[3][1]);
      acc[3][2] = fmaf(pa.w, pg.z, acc[3][2]); acc[3][3] = fmaf(pa.w, pg.w, acc[3][3]);
    }
  }
#pragma unroll
  for (int i = 0; i < 4; ++i) {
    float4 o; o.x = acc[i][0]; o.y = acc[i][1]; o.z = acc[i][2]; o.w = acc[i][3];
    *(float4*)&Rp[(size_t)ks * (K_EIG * K_EIG) + (size_t)(at + a4 + i) * K_EIG + bt + b4] = o;
  }
}

// ---------- kernel 8b: reduce 16 slices + partial trace/triu sums ----------
__global__ __launch_bounds__(256) void k_Rred(const float* __restrict__ Rp,
                                              double* __restrict__ part) {
  const int tid = threadIdx.x;
  const int e0 = blockIdx.x * 1024 + tid * 4;
  float4 s = {0.f, 0.f, 0.f, 0.f};
  for (int ks = 0; ks < 16; ++ks) {
    const float4 v = *(const float4*)&Rp[(size_t)ks * (K_EIG * K_EIG) + e0];
    s.x += v.x; s.y += v.y; s.z += v.z; s.w += v.w;
  }
  const float sc = (10.f / 8192.f) * (10.f / 8192.f);
  double tl = 0.0, rg = 0.0;
#pragma unroll
  for (int j = 0; j < 4; ++j) {
    const int e = e0 + j;
    const int a = e >> 8, b = e & 255;
    const double v = (double)(((const float*)&s)[j] * sc);
    if (a == b) tl += v;
    else if (b > a) rg += v * v;
  }
  __shared__ double st[256], sr[256];
  st[tid] = tl; sr[tid] = rg;
  __syncthreads();
  for (int w = 128; w > 0; w >>= 1) {
    if (tid < w) { st[tid] += st[tid + w]; sr[tid] += sr[tid + w]; }
    __syncthreads();
  }
  if (tid == 0) { part[blockIdx.x] = st[0]; part[64 + blockIdx.x] = sr[0]; }
}

// ---------- kernel 9: fold 64 block partials -> 2 outputs ----------
__global__ void k_final2(const double* __restrict__ part, float* __restrict__ out) {
  const int lane = threadIdx.x;
  double tl = part[lane];
  double rg = part[64 + lane];
  for (int m = 32; m > 0; m >>= 1) {
    tl += __shfl_xor(tl, m, 64);
    rg += __shfl_xor(rg, m, 64);
  }
  if (lane == 0) {
    out[0] = (float)(-tl);
    out[1] = (float)(rg * 0.05);
  }
}

extern "C" void kernel_launch(void* const* d_in, const int* in_sizes, int n_in,
                              void* d_out, int out_size, void* d_ws, size_t ws_size,
                              hipStream_t stream) {
  const float* FF = (const float*)d_in[0];
  const float* Psi = (const float*)d_in[1];
  float* out = (float*)d_out;
  float* ws = (float*)d_ws;

  size_t o = 0;
  ushort_t* FFbf = (ushort_t*)(ws + o); o += (size_t)N_TOK * D_FEAT / 2;
  float* rn  = ws + o; o += N_TOK;
  float* sqv = ws + o; o += N_TOK;
  float* pd  = ws + o; o += (size_t)N_TOK * NCHUNK * 16;
  int*   pi  = (int*)(ws + o); o += (size_t)N_TOK * NCHUNK * 16;
  float* tv  = ws + o; o += (size_t)N_TOK * KNN;
  int*   tj  = (int*)(ws + o); o += (size_t)N_TOK * KNN;
  int*   cnt = (int*)(ws + o); o += N_TOK;
  double* part = (double*)(ws + o); o += 256;  // 128 doubles
  ushort_t* Gmax = (ushort_t*)(ws + o); o += (size_t)N_TOK * 256 / 2;  // 4 MB
  // region X (32 MB, size of Cs): Cs dead after k_rescore, then reused:
  //   nbrJ (8MB) | nbrW (8MB) | Dv (32KB) | gP (8MB) | Rp (4MB at +25MB)
  char* X = (char*)(ws + o);
  ushort_t* Cs = (ushort_t*)X;
  int*   nbrJ = (int*)X;
  float* nbrW = (float*)(X + (size_t)N_TOK * CAP * 4);
  float* Dv   = (float*)(X + 2 * (size_t)N_TOK * CAP * 4);
  float* gP   = (float*)(X + 2 * (size_t)N_TOK * CAP * 4 + (size_t)N_TOK * 4);
  float* Rp   = (float*)(X + 25ull * 1024 * 1024);

  k_norm<<<N_TOK, 192, 0, stream>>>(FF, FFbf, rn, sqv);
  for (int c = 0; c < NCHUNK; ++c) {
    k_gemm<<<(N_TOK / 256) * (CHUNK / 256), 512, 0, stream>>>(FFbf, Cs, Gmax, c * CHUNK);
    k_sel<<<N_TOK / 4, 256, 0, stream>>>(Cs, Gmax, c, pd, pi);
  }
  k_rescore<<<N_TOK / 4, 256, 0, stream>>>(FF, rn, sqv, pd, pi, tv, tj, cnt);
  k_scatter<<<(N_TOK * KNN + 255) / 256, 256, 0, stream>>>(tv, tj, cnt, nbrJ, nbrW);
  k_degree<<<N_TOK / 4, 256, 0, stream>>>(cnt, nbrW, Dv);
  k_gpsi<<<N_TOK, 256, 0, stream>>>(Psi, cnt, nbrJ, nbrW, Dv, gP);
  k_Rpart<<<256, 256, 0, stream>>>(Psi, gP, Rp);
  k_Rred<<<64, 256, 0, stream>>>(Rp, part);
  k_final2<<<1, 64, 0, stream>>>(part, out);
}